// Round 17
// baseline (64.899 us; speedup 1.0000x reference)
//
#include <hip/hip_runtime.h>

// Problem constants
#define TT   512
#define BB   32
#define TS_F 76
#define N_WF 200
#define WF_LEN 1000
#define TEXT_D 200
#define WF_D 100
#define HID  256
#define FC_H 256
#define ROWS (TT*BB)              // 16384
#define K1REAL 556

// K-order for s4: [0,200) texts | [200,224) zeros | [224,608) feat2 (fc=k-224)
// chunks 0..6 texts (staged pipeline), 7..14 featA (direct per-wave),
// 15..18 spread (LDS)
#define K4_NCH  19

// ---- fragment-packed B geometry (pre-split hi/lo, MFMA 16x16x32 layout)
#define S1_NJ     7                       // 112 cols (100 real)
#define WWF_STEP  (S1_NJ*1024)            // 7168 shorts per K-step
#define WWF_TOT   (32*WWF_STEP)           // 229376
#define S2_NSTEP  3                       // K = 96 (76 real)
#define WTS_STEP  (16*1024)
#define WTS_TOT   (S2_NSTEP*WTS_STEP)     // 49152
#define W1F_STEP  (16*1024)
#define W1F_TOT   (K4_NCH*W1F_STEP)       // 311296
#define K3_NSTEP  7                       // K = 224 (200 real)
#define K3_NJ     8                       // 128 cols (100 real)
#define WFO3_PER_B (K3_NSTEP*K3_NJ*1024)  // 57344 shorts per batch b
#define WFO3_TOT  (BB*WFO3_PER_B)         // 1835008

// featA: A-fragment feature planes (ts_out only) [rt 256][cf 8][ri 4][lane 64][q 8]
#define FA_TOT    (256LL*8*4*512)         // 4194304 shorts per plane

// s1 split-K partials: partT[z][bb][c(112)][n(224)] f32
#define S1_Z      4
#define PART_C    112
#define PART_N    224
#define PART_PER_Z (BB*PART_C*PART_N)     // 802816 f32

typedef __attribute__((ext_vector_type(8))) short short8;
typedef __attribute__((ext_vector_type(4))) short sshort4;
typedef __attribute__((ext_vector_type(4))) float f32x4;

// Truncating bf16 split: hi = v low-16-zeroed (exact subtraction), lo = residual.
__device__ __forceinline__ void split_bf16(float v, short& h, short& l) {
    unsigned u = __builtin_bit_cast(unsigned, v);
    unsigned hu = u & 0xFFFF0000u;
    h = (short)(hu >> 16);
    float r = v - __builtin_bit_cast(float, hu);
    l = (short)(__builtin_bit_cast(unsigned, r) >> 16);
}

// featA element address, fc in [0,256) only (cf stride 8)
__device__ __forceinline__ long long fa_addr(int r, int fc) {
    int rt = r >> 6, ri = (r >> 4) & 3, lrow = r & 15;
    int cf = fc >> 5, cg = (fc >> 3) & 3, q = fc & 7;
    return ((((long long)rt * 8 + cf) * 4 + ri) << 9) + ((lrow + cg * 16) << 3) + q;
}

// direct A-fragment loader: lane supplies A[row][k0..k0+7], guarded, split
__device__ __forceinline__ void loadA_frag(const float* __restrict__ rowp,
                                           int k0, int kreal,
                                           short8& a_h, short8& a_l) {
    float va[8];
    if (k0 + 8 <= kreal) {
        float4 t0 = ((const float4*)(rowp + k0))[0];
        float4 t1 = ((const float4*)(rowp + k0))[1];
        va[0]=t0.x; va[1]=t0.y; va[2]=t0.z; va[3]=t0.w;
        va[4]=t1.x; va[5]=t1.y; va[6]=t1.z; va[7]=t1.w;
    } else {
        #pragma unroll
        for (int q = 0; q < 8; q++) va[q] = (k0 + q < kreal) ? rowp[k0 + q] : 0.f;
    }
    #pragma unroll
    for (int q = 0; q < 8; q++) { short h, s; split_bf16(va[q], h, s); a_h[q]=h; a_l[q]=s; }
}

// ============ K0: packs needed by K1 only =================================
__global__ __launch_bounds__(256)
void k0_prep(const float* __restrict__ W_wf, const float* __restrict__ W_ts,
             short* __restrict__ wwfF, short* __restrict__ wtsF)
{
    const int b = blockIdx.x, tid = threadIdx.x;
    if (b < 56) {                       // wwf: 32 steps x 7 tiles x 64 lanes
        int idx = b*256 + tid;          // [0,14336)
        int l = idx & 63;
        int t = idx >> 6;               // 0..223
        int jt = t % 7, st = t / 7;
        int c = jt*16 + (l & 15), lq = l >> 4;
        short8 h8, l8;
        #pragma unroll
        for (int q = 0; q < 8; q++) {
            int k = st*32 + lq*8 + q;
            float v = (k < WF_LEN && c < WF_D) ? W_wf[k*WF_D + c] : 0.f;
            short h, s; split_bf16(v, h, s); h8[q]=h; l8[q]=s;
        }
        int off = (st*7 + jt)*1024 + l*8;
        *(short8*)(wwfF + off)       = h8;
        *(short8*)(wwfF + off + 512) = l8;
    } else {                            // wts: 3 steps x 16 tiles x 64 lanes
        int idx = (b-56)*256 + tid;     // [0,3072)
        int l = idx & 63, jj = (idx>>6) & 15, st = idx >> 10;
        int c = jj*16 + (l&15), lq = l >> 4;
        short8 h8, l8;
        #pragma unroll
        for (int q = 0; q < 8; q++) {
            int k = st*32 + lq*8 + q;
            float v = (k < TS_F) ? W_ts[k*HID + c] : 0.f;
            short h, s; split_bf16(v, h, s); h8[q]=h; l8[q]=s;
        }
        int off = (st*16 + jj)*1024 + l*8;
        *(short8*)(wtsF + off)       = h8;
        *(short8*)(wtsF + off + 512) = l8;
    }
}

// ============ K1 (R7-proven): s1 direct-A 64-row + s2 direct-A =============
__global__ __launch_bounds__(256)
void k1_main(const float* __restrict__ wf, const float* __restrict__ ts,
             const float* __restrict__ b_ts,
             const short* __restrict__ wwfF, const short* __restrict__ wtsF,
             float* __restrict__ partT,
             short* __restrict__ featAH, short* __restrict__ featAL)
{
    __shared__ float smemF[4224];    // s2 epilogue [64][66] transpose buf only

    const int b = blockIdx.x, tid = threadIdx.x;
    const int wv = tid >> 6, lane = tid & 63;
    const int m16 = lane & 15, quad = lane >> 4;

    if (b < 400) {
        // ---------------- s1 (split-K z = b/100), NO LDS, NO barriers -----
        const int by = b % 100, z = b / 100;
        const int row0 = by * 64;
        const float* rowp = wf + (long long)(row0 + wv*16 + m16) * WF_LEN;
        const int kb = z * 256 + quad * 8;

        f32x4 acc[7];
        #pragma unroll
        for (int j = 0; j < 7; j++) acc[j] = f32x4{0.f, 0.f, 0.f, 0.f};

        #pragma unroll 2
        for (int cl = 0; cl < 8; ++cl) {
            short8 a_h, a_l;
            loadA_frag(rowp, kb + cl*32, WF_LEN, a_h, a_l);

            const short* fb = wwfF + (z*8 + cl) * WWF_STEP + lane * 8;
            short8 bh[7], bl[7];
            #pragma unroll
            for (int j = 0; j < 7; j++) {
                bh[j] = *(const short8*)(fb + j * 1024);
                bl[j] = *(const short8*)(fb + j * 1024 + 512);
            }
            #pragma unroll
            for (int j = 0; j < 7; j++) {
                acc[j] = __builtin_amdgcn_mfma_f32_16x16x32_bf16(a_h, bh[j], acc[j], 0, 0, 0);
                acc[j] = __builtin_amdgcn_mfma_f32_16x16x32_bf16(a_h, bl[j], acc[j], 0, 0, 0);
                acc[j] = __builtin_amdgcn_mfma_f32_16x16x32_bf16(a_l, bh[j], acc[j], 0, 0, 0);
            }
        }

        // f32 partial store (float4, disjoint per z -> deterministic)
        float* Cb = partT + (long long)z * PART_PER_Z;
        const int r = row0 + wv*16 + quad*4;          // 4-aligned, never crosses bb
        const int bb2 = r / N_WF, n = r - bb2 * N_WF;
        #pragma unroll
        for (int j = 0; j < 7; j++) {
            int cc = j * 16 + m16;
            if (cc >= WF_D) continue;
            float4 t;
            t.x = acc[j][0]; t.y = acc[j][1]; t.z = acc[j][2]; t.w = acc[j][3];
            *(float4*)&Cb[((long long)bb2 * PART_C + cc) * PART_N + n] = t;
        }
    } else {
        // ---------------- s2: direct-A, barriers only in epilogue ---------
        const int id2 = b - 400;
        const int bx = id2 & 3, by = id2 >> 2;
        const int row0 = by * 64, col0 = bx * 64;
        const float* rowp = ts + (long long)(row0 + wv*16 + m16) * TS_F;

        f32x4 acc[4];
        #pragma unroll
        for (int j = 0; j < 4; j++) acc[j] = f32x4{0.f, 0.f, 0.f, 0.f};

        #pragma unroll
        for (int st = 0; st < S2_NSTEP; ++st) {
            short8 a_h, a_l;
            loadA_frag(rowp, st*32 + quad*8, TS_F, a_h, a_l);

            const short* fb = wtsF + st * WTS_STEP + (bx*4) * 1024 + lane * 8;
            #pragma unroll
            for (int j = 0; j < 4; j++) {
                short8 b_h = *(const short8*)(fb + j * 1024);
                short8 b_l = *(const short8*)(fb + j * 1024 + 512);
                acc[j] = __builtin_amdgcn_mfma_f32_16x16x32_bf16(a_h, b_h, acc[j], 0, 0, 0);
                acc[j] = __builtin_amdgcn_mfma_f32_16x16x32_bf16(a_h, b_l, acc[j], 0, 0, 0);
                acc[j] = __builtin_amdgcn_mfma_f32_16x16x32_bf16(a_l, b_h, acc[j], 0, 0, 0);
            }
        }

        // epilogue: tanh -> LDS [64][66] transpose -> short8 featA stores
        #pragma unroll
        for (int j = 0; j < 4; j++) {
            float bv = b_ts[col0 + j*16 + m16];
            #pragma unroll
            for (int rr = 0; rr < 4; rr++)
                smemF[(wv*16 + quad*4 + rr)*66 + j*16 + m16] = tanhf(acc[j][rr] + bv);
        }
        __syncthreads();
        #pragma unroll
        for (int i = 0; i < 2; i++) {
            int task = i*256 + tid;          // 512 tasks = 64 rows x 8 col-groups
            int rl = task >> 3, cg = task & 7;
            const float* p = &smemF[rl*66 + cg*8];
            short8 h8, l8;
            #pragma unroll
            for (int q = 0; q < 8; q++) { short h, s; split_bf16(p[q], h, s); h8[q]=h; l8[q]=s; }
            long long fo = fa_addr(row0 + rl, col0 + cg*8);
            *(short8*)(featAH + fo) = h8;
            *(short8*)(featAL + fo) = l8;
        }
    }
}

// ---- K2: reduce z-slices -> wfo3F frag layout + w1F pack ------------------
__global__ __launch_bounds__(256)
void k2_reduce(const float* __restrict__ partT, const float* __restrict__ b_wf,
               const float* __restrict__ W1,
               short* __restrict__ wfo3F, short* __restrict__ w1F)
{
    const int blk = blockIdx.x, tid = threadIdx.x;
    if (blk < 448) {
        const int bb = blk / 14, rem = blk % 14;
        const int st = rem >> 1, half = rem & 1;
        const int j = half * 4 + (tid >> 6);
        const int g = tid & 63;
        const int m16 = g & 15, kk8 = g >> 4;
        const int c = j * 16 + m16;
        const int n = st * 32 + kk8 * 8;

        float v[8];
        if (c < WF_D && n < N_WF) {
            float bw = b_wf[c];
            #pragma unroll
            for (int q = 0; q < 8; q++) v[q] = bw;
            #pragma unroll
            for (int z = 0; z < S1_Z; z++) {
                const float* p = partT + (long long)z * PART_PER_Z
                               + ((long long)bb * PART_C + c) * PART_N + n;
                float4 t0 = ((const float4*)p)[0];
                float4 t1 = ((const float4*)p)[1];
                v[0]+=t0.x; v[1]+=t0.y; v[2]+=t0.z; v[3]+=t0.w;
                v[4]+=t1.x; v[5]+=t1.y; v[6]+=t1.z; v[7]+=t1.w;
            }
        } else {
            #pragma unroll
            for (int q = 0; q < 8; q++) v[q] = 0.f;
        }
        short8 h8, l8;
        #pragma unroll
        for (int q = 0; q < 8; q++) { short h, s; split_bf16(v[q], h, s); h8[q]=h; l8[q]=s; }
        long long base = (long long)bb * WFO3_PER_B + st * (K3_NJ*1024) + j * 1024 + g * 8;
        *(short8*)(wfo3F + base)       = h8;
        *(short8*)(wfo3F + base + 512) = l8;
    } else {                            // w1F pack: 19 chunks x 16 tiles x 64 lanes
        int idx = (blk-448)*256 + tid;  // [0,19456)
        int l = idx & 63, t = idx >> 6;
        int jj = t & 15, ch = t >> 4;
        int n = jj*16 + (l&15), lq = l >> 4;
        short8 h8, l8;
        #pragma unroll
        for (int q = 0; q < 8; q++) {
            int k = ch*32 + lq*8 + q;    // K-order index [0,608)
            float v = 0.f;
            if (k < 200)                  v = W1[k*FC_H + n];
            else if (k >= 224 && k < 580) v = W1[(k-24)*FC_H + n];
            short h, s; split_bf16(v, h, s); h8[q]=h; l8[q]=s;
        }
        int off = (ch*16 + jj)*1024 + l*8;
        *(short8*)(w1F + off)       = h8;
        *(short8*)(w1F + off + 512) = l8;
    }
}

// ====== K4 fused (R16 + direct featA): XCD-grouped swizzle; phase A = s3
//   spread into LDS A-frags; phase B1 = texts chunks 0..6 staged pipeline;
//   phase B2 = featA chunks 7..14 DIRECT per-wave (no staging, no barriers,
//   2-deep register prefetch); 15..18 from LDS; LDS-reduce head. ===========
__global__ __launch_bounds__(512)
void k4_fused(const float* __restrict__ wwm, const float* __restrict__ texts,
              const short* __restrict__ wfo3F,
              const short* __restrict__ featAH, const short* __restrict__ featAL,
              const short* __restrict__ w1F,
              const float* __restrict__ b1, const float* __restrict__ W2,
              const float* __restrict__ b2, float* __restrict__ out)
{
    __shared__ short AhB[2][2048], AlB[2][2048];   // 16 KB texts A dbuf
    __shared__ short fLH[4][2048], fLL[4][2048];   // 32 KB spread A-frags
    __shared__ float transF[64*132];               // 33.8 KB (phase A only)
    __shared__ float ored[8][64][2];               // 4 KB (epilogue)

    const int tid = threadIdx.x;
    const int wv = tid >> 6, lane = tid & 63;
    const int m16 = lane & 15, quad = lane >> 4;
    // XCD-grouped swizzle (bijective on [0,256))
    const int bid = blockIdx.x;
    const int rt = ((bid & 7) << 5) | (bid >> 3);
    const int row0 = rt * 64;
    const int fsw = (quad ^ ((m16 >> 1) & 3)) * 8;

    // ---------------- Phase A: s3 for this block's 64 rows ----------------
    {
        const int bz = rt >> 3, by = rt & 7;
        const int bx3 = wv >> 2, wrow = wv & 3;
        const float* rowp3 = wwm + ((long long)bz * TT + by*64 + wrow*16 + m16) * N_WF;
        const short* FB = wfo3F + (long long)bz * WFO3_PER_B;

        f32x4 acc3[4];
        #pragma unroll
        for (int j = 0; j < 4; j++) acc3[j] = f32x4{0.f, 0.f, 0.f, 0.f};

        #pragma unroll 2
        for (int st = 0; st < K3_NSTEP; ++st) {
            short8 a_h, a_l;
            loadA_frag(rowp3, st*32 + quad*8, N_WF, a_h, a_l);
            const short* fb = FB + st * (K3_NJ*1024) + (bx3*4) * 1024 + lane * 8;
            #pragma unroll
            for (int j = 0; j < 4; j++) {
                short8 b_h = *(const short8*)(fb + j * 1024);
                short8 b_l = *(const short8*)(fb + j * 1024 + 512);
                acc3[j] = __builtin_amdgcn_mfma_f32_16x16x32_bf16(a_h, b_h, acc3[j], 0, 0, 0);
                acc3[j] = __builtin_amdgcn_mfma_f32_16x16x32_bf16(a_h, b_l, acc3[j], 0, 0, 0);
                acc3[j] = __builtin_amdgcn_mfma_f32_16x16x32_bf16(a_l, b_h, acc3[j], 0, 0, 0);
            }
        }
        // transpose stage: rows 0..63 x cols 0..127 (cols>=100 zero via wfo3F pad)
        #pragma unroll
        for (int j = 0; j < 4; j++)
            #pragma unroll
            for (int rr = 0; rr < 4; rr++)
                transF[(wrow*16 + quad*4 + rr)*132 + bx3*64 + j*16 + m16] =
                    acc3[j][rr] * (1.0f / N_WF);
    }
    __syncthreads();
    // build spread A-frags in LDS: 1024 slots = [cf 4][ri 4][lane 64]
    #pragma unroll
    for (int i = 0; i < 2; i++) {
        int slot = tid*2 + i;
        int l = slot & 63, ri = (slot >> 6) & 3, cf = slot >> 8;
        int lrow = l & 15, cg = l >> 4;
        const float* p = &transF[(ri*16 + lrow)*132 + cf*32 + cg*8];
        short8 h8, l8;
        #pragma unroll
        for (int q = 0; q < 8; q++) { short h, s; split_bf16(p[q], h, s); h8[q]=h; l8[q]=s; }
        *(short8*)&fLH[cf][(ri << 9) + l*8] = h8;
        *(short8*)&fLL[cf][(ri << 9) + l*8] = l8;
    }
    __syncthreads();

    // ---------------- Phase B: common state --------------------------------
    const int ar  = tid >> 2;
    const int ag  = tid & 3;
    const int asw = (ag ^ ((ar >> 1) & 3)) * 8;
    const long long gr = row0 + ar;

    f32x4 acc[4][2];
    #pragma unroll
    for (int i = 0; i < 4; i++)
        #pragma unroll
        for (int j = 0; j < 2; j++) acc[i][j] = f32x4{0.f, 0.f, 0.f, 0.f};

    auto loadB2 = [&](int c, short8* bh, short8* bl) {
        #pragma unroll
        for (int ci = 0; ci < 2; ci++) {
            const short* fb = w1F + (c * 16 + wv * 2 + ci) * 1024 + lane * 8;
            bh[ci] = *(const short8*)fb;
            bl[ci] = *(const short8*)(fb + 512);
        }
    };

    // ---------------- Phase B1: texts chunks 0..6 (staged P/Q pipeline) ----
    {
        float  vaP[8], vaQ[8];
        short8 vbhP[2], vblP[2], vbhQ[2], vblQ[2];

        auto loadTexts = [&](int c, float* va) {
            if (tid < 256) {
                int kc = c * 32 + ag * 8;
                if (kc + 8 <= TEXT_D) {
                    const float4* p = (const float4*)(texts + gr * TEXT_D + kc);
                    float4 t0 = p[0], t1 = p[1];
                    va[0]=t0.x; va[1]=t0.y; va[2]=t0.z; va[3]=t0.w;
                    va[4]=t1.x; va[5]=t1.y; va[6]=t1.z; va[7]=t1.w;
                } else {
                    #pragma unroll
                    for (int q = 0; q < 8; q++) va[q] = 0.f;
                }
            }
        };
        auto storeTexts = [&](const float* va, int buf) {
            if (tid < 256) {
                short8 h8, l8;
                #pragma unroll
                for (int q = 0; q < 8; q++) { short h, s; split_bf16(va[q], h, s); h8[q]=h; l8[q]=s; }
                *(short8*)&AhB[buf][ar*32 + asw] = h8;
                *(short8*)&AlB[buf][ar*32 + asw] = l8;
            }
        };
        auto mfmaTexts = [&](int buf, const short8 bh[2], const short8 bl[2]) {
            short8 a_h[4], a_l[4];
            #pragma unroll
            for (int ri = 0; ri < 4; ri++) {
                a_h[ri] = *(const short8*)&AhB[buf][(ri*16 + m16)*32 + fsw];
                a_l[ri] = *(const short8*)&AlB[buf][(ri*16 + m16)*32 + fsw];
            }
            #pragma unroll
            for (int ci = 0; ci < 2; ci++)
                #pragma unroll
                for (int ri = 0; ri < 4; ri++) {
                    acc[ri][ci] = __builtin_amdgcn_mfma_f32_16x16x32_bf16(a_h[ri], bh[ci], acc[ri][ci], 0, 0, 0);
                    acc[ri][ci] = __builtin_amdgcn_mfma_f32_16x16x32_bf16(a_h[ri], bl[ci], acc[ri][ci], 0, 0, 0);
                    acc[ri][ci] = __builtin_amdgcn_mfma_f32_16x16x32_bf16(a_l[ri], bh[ci], acc[ri][ci], 0, 0, 0);
                }
        };

        loadTexts(0, vaP); loadB2(0, vbhP, vblP);
        loadTexts(1, vaQ); loadB2(1, vbhQ, vblQ);
        storeTexts(vaP, 0);
        __syncthreads();

        for (int c = 0; c < 7; c += 2) {
            // even chunk c (buf 0)
            {
                short8 bh[2] = {vbhP[0], vbhP[1]};
                short8 bl[2] = {vblP[0], vblP[1]};
                if (c + 2 < 7) { loadTexts(c + 2, vaP); loadB2(c + 2, vbhP, vblP); }
                mfmaTexts(0, bh, bl);
                if (c + 1 < 7) { storeTexts(vaQ, 1); __syncthreads(); }
            }
            // odd chunk c+1 (buf 1)
            if (c + 1 < 7) {
                short8 bh[2] = {vbhQ[0], vbhQ[1]};
                short8 bl[2] = {vblQ[0], vblQ[1]};
                if (c + 3 < 7) { loadTexts(c + 3, vaQ); loadB2(c + 3, vbhQ, vblQ); }
                mfmaTexts(1, bh, bl);
                if (c + 2 < 7) { storeTexts(vaP, 0); __syncthreads(); }
            }
        }
    }

    // ---------- Phase B2: featA chunks 7..14, direct per-wave, no barriers --
    {
        short8 cah[4], cal[4], cbh[2], cbl[2];
        short8 nah[4], nal[4], nbh[2], nbl[2];

        auto loadFeatDir = [&](int c, short8* ah, short8* al) {
            const long long base = (((long long)rt * 8 + (c - 7)) << 11) + lane * 8;
            #pragma unroll
            for (int ri = 0; ri < 4; ri++) {
                ah[ri] = *(const short8*)(featAH + base + ri*512);
                al[ri] = *(const short8*)(featAL + base + ri*512);
            }
        };

        loadFeatDir(7, cah, cal); loadB2(7, cbh, cbl);
        #pragma unroll
        for (int c = 7; c < 15; ++c) {
            if (c + 1 < 15) { loadFeatDir(c + 1, nah, nal); loadB2(c + 1, nbh, nbl); }
            #pragma unroll
            for (int ci = 0; ci < 2; ci++)
                #pragma unroll
                for (int ri = 0; ri < 4; ri++) {
                    acc[ri][ci] = __builtin_amdgcn_mfma_f32_16x16x32_bf16(cah[ri], cbh[ci], acc[ri][ci], 0, 0, 0);
                    acc[ri][ci] = __builtin_amdgcn_mfma_f32_16x16x32_bf16(cah[ri], cbl[ci], acc[ri][ci], 0, 0, 0);
                    acc[ri][ci] = __builtin_amdgcn_mfma_f32_16x16x32_bf16(cal[ri], cbh[ci], acc[ri][ci], 0, 0, 0);
                }
            if (c + 1 < 15) {
                #pragma unroll
                for (int i = 0; i < 4; i++) { cah[i] = nah[i]; cal[i] = nal[i]; }
                #pragma unroll
                for (int i = 0; i < 2; i++) { cbh[i] = nbh[i]; cbl[i] = nbl[i]; }
            }
        }
    }

    // chunks 15..18: A from LDS spread frags (phase A data, still valid)
    #pragma unroll
    for (int c = 15; c < 19; ++c) {
        short8 bh[2], bl[2];
        loadB2(c, bh, bl);
        const int f = c - 15;
        short8 a_h[4], a_l[4];
        #pragma unroll
        for (int ri = 0; ri < 4; ri++) {
            a_h[ri] = *(const short8*)&fLH[f][ri*512 + lane*8];
            a_l[ri] = *(const short8*)&fLL[f][ri*512 + lane*8];
        }
        #pragma unroll
        for (int ci = 0; ci < 2; ci++)
            #pragma unroll
            for (int ri = 0; ri < 4; ri++) {
                acc[ri][ci] = __builtin_amdgcn_mfma_f32_16x16x32_bf16(a_h[ri], bh[ci], acc[ri][ci], 0, 0, 0);
                acc[ri][ci] = __builtin_amdgcn_mfma_f32_16x16x32_bf16(a_h[ri], bl[ci], acc[ri][ci], 0, 0, 0);
                acc[ri][ci] = __builtin_amdgcn_mfma_f32_16x16x32_bf16(a_l[ri], bh[ci], acc[ri][ci], 0, 0, 0);
            }
    }

    // epilogue: relu + head partials, per-wave 16-lane reduce, LDS cross-wave
    float o0[4][4] = {}, o1[4][4] = {};
    #pragma unroll
    for (int ci = 0; ci < 2; ci++) {
        int C = wv * 32 + ci * 16 + m16;
        float bv  = b1[C];
        float w20 = W2[C * 2 + 0];
        float w21 = W2[C * 2 + 1];
        #pragma unroll
        for (int ri = 0; ri < 4; ri++)
            #pragma unroll
            for (int rr = 0; rr < 4; rr++) {
                float v = fmaxf(acc[ri][ci][rr] + bv, 0.f);
                o0[ri][rr] += v * w20;
                o1[ri][rr] += v * w21;
            }
    }
    __syncthreads();
    #pragma unroll
    for (int ri = 0; ri < 4; ri++)
        #pragma unroll
        for (int rr = 0; rr < 4; rr++) {
            float s0 = o0[ri][rr], s1 = o1[ri][rr];
            #pragma unroll
            for (int mk = 1; mk < 16; mk <<= 1) {
                s0 += __shfl_xor(s0, mk);
                s1 += __shfl_xor(s1, mk);
            }
            if (m16 == 0) {
                int rl = ri * 16 + quad * 4 + rr;
                ored[wv][rl][0] = s0;
                ored[wv][rl][1] = s1;
            }
        }
    __syncthreads();
    if (tid < 128) {
        int rl = tid >> 1, cc = tid & 1;
        float s = b2[cc];
        #pragma unroll
        for (int w = 0; w < 8; w++) s += ored[w][rl][cc];
        out[(long long)(row0 + rl) * 2 + cc] = s;
    }
}

extern "C" void kernel_launch(void* const* d_in, const int* in_sizes, int n_in,
                              void* d_out, int out_size, void* d_ws, size_t ws_size,
                              hipStream_t stream)
{
    const float* texts = (const float*)d_in[0];   // (512,32,200)
    const float* ts    = (const float*)d_in[1];   // (512,32,76)
    const float* wf    = (const float*)d_in[2];   // (32,200,1000)
    const float* wwm   = (const float*)d_in[3];   // (32,512,200)
    const float* W_wf  = (const float*)d_in[4];   // (1000,100)
    const float* b_wf  = (const float*)d_in[5];
    const float* W_ts  = (const float*)d_in[6];   // (76,256)
    const float* b_ts  = (const float*)d_in[7];
    const float* W1    = (const float*)d_in[8];   // (556,256)
    const float* b1    = (const float*)d_in[9];
    const float* W2    = (const float*)d_in[10];  // (256,2)
    const float* b2    = (const float*)d_in[11];
    float* out = (float*)d_out;

    // ---- workspace layout (all disjoint, ~35 MB) ----
    float* partT  = (float*)d_ws;                      // 4*802816 f32
    short* wwfF   = (short*)(partT + S1_Z * PART_PER_Z);
    short* wtsF   = wwfF + WWF_TOT;
    short* w1F    = wtsF + WTS_TOT;
    short* wfo3F  = w1F + W1F_TOT;
    short* featAH = wfo3F + WFO3_TOT;                  // ts_out frag planes
    short* featAL = featAH + FA_TOT;

    // 0) packs k1 needs (wwfF, wtsF)
    k0_prep<<<68, 256, 0, stream>>>(W_wf, W_ts, wwfF, wtsF);

    // 1) s1 split-K partials + s2 (featA cf 0..7)
    k1_main<<<1424, 256, 0, stream>>>(wf, ts, b_ts, wwfF, wtsF,
                                      partT, featAH, featAL);

    // 2) reduce -> wfo3F frag layout + w1F pack
    k2_reduce<<<524, 256, 0, stream>>>(partT, b_wf, W1, wfo3F, w1F);

    // 3) fused s3 + s4 + head (XCD swizzle; featA chunks direct per-wave)
    k4_fused<<<ROWS / 64, 512, 0, stream>>>(wwm, texts, wfo3F,
                                            featAH, featAL,
                                            w1F, b1, W2, b2, out);
}

// Round 18
// 61.367 us; speedup vs baseline: 1.0576x; 1.0576x over previous
//
#include <hip/hip_runtime.h>

// Problem constants
#define TT   512
#define BB   32
#define TS_F 76
#define N_WF 200
#define WF_LEN 1000
#define TEXT_D 200
#define WF_D 100
#define HID  256
#define FC_H 256
#define ROWS (TT*BB)              // 16384
#define K1REAL 556

// K-order for s4: [0,200) texts | [200,224) zeros | [224,608) feat2 (fc=k-224)
// chunks 0..6 texts, 7..14 featA (cf 0..7 = ts_out), 15..18 LDS (spread cols)
#define K4_NCH  19
#define K4G_NCH 15                // global-memory chunks

// ---- fragment-packed B geometry (pre-split hi/lo, MFMA 16x16x32 layout)
#define S1_NJ     7                       // 112 cols (100 real)
#define WWF_STEP  (S1_NJ*1024)            // 7168 shorts per K-step
#define WWF_TOT   (32*WWF_STEP)           // 229376
#define S2_NSTEP  3                       // K = 96 (76 real)
#define WTS_STEP  (16*1024)
#define WTS_TOT   (S2_NSTEP*WTS_STEP)     // 49152
#define W1F_STEP  (16*1024)
#define W1F_TOT   (K4_NCH*W1F_STEP)       // 311296
#define K3_NSTEP  7                       // K = 224 (200 real)
#define K3_NJ     8                       // 128 cols (100 real)
#define WFO3_PER_B (K3_NSTEP*K3_NJ*1024)  // 57344 shorts per batch b
#define WFO3_TOT  (BB*WFO3_PER_B)         // 1835008

// featA: A-fragment feature planes (ts_out only) [rt 256][cf 8][ri 4][lane 64][q 8]
#define FA_TOT    (256LL*8*4*512)         // 4194304 shorts per plane

// s1 split-K partials: partT[z][bb][c(112)][n(224)] f32
#define S1_Z      4
#define PART_C    112
#define PART_N    224
#define PART_PER_Z (BB*PART_C*PART_N)     // 802816 f32

typedef __attribute__((ext_vector_type(8))) short short8;
typedef __attribute__((ext_vector_type(4))) short sshort4;
typedef __attribute__((ext_vector_type(4))) float f32x4;

// Truncating bf16 split: hi = v low-16-zeroed (exact subtraction), lo = residual.
__device__ __forceinline__ void split_bf16(float v, short& h, short& l) {
    unsigned u = __builtin_bit_cast(unsigned, v);
    unsigned hu = u & 0xFFFF0000u;
    h = (short)(hu >> 16);
    float r = v - __builtin_bit_cast(float, hu);
    l = (short)(__builtin_bit_cast(unsigned, r) >> 16);
}

// featA element address, fc in [0,256) only (cf stride 8)
__device__ __forceinline__ long long fa_addr(int r, int fc) {
    int rt = r >> 6, ri = (r >> 4) & 3, lrow = r & 15;
    int cf = fc >> 5, cg = (fc >> 3) & 3, q = fc & 7;
    return ((((long long)rt * 8 + cf) * 4 + ri) << 9) + ((lrow + cg * 16) << 3) + q;
}

// direct A-fragment loader: lane supplies A[row][k0..k0+7], guarded, split
__device__ __forceinline__ void loadA_frag(const float* __restrict__ rowp,
                                           int k0, int kreal,
                                           short8& a_h, short8& a_l) {
    float va[8];
    if (k0 + 8 <= kreal) {
        float4 t0 = ((const float4*)(rowp + k0))[0];
        float4 t1 = ((const float4*)(rowp + k0))[1];
        va[0]=t0.x; va[1]=t0.y; va[2]=t0.z; va[3]=t0.w;
        va[4]=t1.x; va[5]=t1.y; va[6]=t1.z; va[7]=t1.w;
    } else {
        #pragma unroll
        for (int q = 0; q < 8; q++) va[q] = (k0 + q < kreal) ? rowp[k0 + q] : 0.f;
    }
    #pragma unroll
    for (int q = 0; q < 8; q++) { short h, s; split_bf16(va[q], h, s); a_h[q]=h; a_l[q]=s; }
}

// ============ K0: packs needed by K1 only =================================
__global__ __launch_bounds__(256)
void k0_prep(const float* __restrict__ W_wf, const float* __restrict__ W_ts,
             short* __restrict__ wwfF, short* __restrict__ wtsF)
{
    const int b = blockIdx.x, tid = threadIdx.x;
    if (b < 56) {                       // wwf: 32 steps x 7 tiles x 64 lanes
        int idx = b*256 + tid;          // [0,14336)
        int l = idx & 63;
        int t = idx >> 6;               // 0..223
        int jt = t % 7, st = t / 7;
        int c = jt*16 + (l & 15), lq = l >> 4;
        short8 h8, l8;
        #pragma unroll
        for (int q = 0; q < 8; q++) {
            int k = st*32 + lq*8 + q;
            float v = (k < WF_LEN && c < WF_D) ? W_wf[k*WF_D + c] : 0.f;
            short h, s; split_bf16(v, h, s); h8[q]=h; l8[q]=s;
        }
        int off = (st*7 + jt)*1024 + l*8;
        *(short8*)(wwfF + off)       = h8;
        *(short8*)(wwfF + off + 512) = l8;
    } else {                            // wts: 3 steps x 16 tiles x 64 lanes
        int idx = (b-56)*256 + tid;     // [0,3072)
        int l = idx & 63, jj = (idx>>6) & 15, st = idx >> 10;
        int c = jj*16 + (l&15), lq = l >> 4;
        short8 h8, l8;
        #pragma unroll
        for (int q = 0; q < 8; q++) {
            int k = st*32 + lq*8 + q;
            float v = (k < TS_F) ? W_ts[k*HID + c] : 0.f;
            short h, s; split_bf16(v, h, s); h8[q]=h; l8[q]=s;
        }
        int off = (st*16 + jj)*1024 + l*8;
        *(short8*)(wtsF + off)       = h8;
        *(short8*)(wtsF + off + 512) = l8;
    }
}

// ============ K1: s1 direct-A 64-row (XCD-grouped z) + s2 direct-A =========
__global__ __launch_bounds__(256)
void k1_main(const float* __restrict__ wf, const float* __restrict__ ts,
             const float* __restrict__ b_ts,
             const short* __restrict__ wwfF, const short* __restrict__ wtsF,
             float* __restrict__ partT,
             short* __restrict__ featAH, short* __restrict__ featAL)
{
    __shared__ float smemF[4224];    // s2 epilogue [64][66] transpose buf only

    const int b = blockIdx.x, tid = threadIdx.x;
    const int wv = tid >> 6, lane = tid & 63;
    const int m16 = lane & 15, quad = lane >> 4;

    if (b < 400) {
        // ---------------- s1 (split-K), NO LDS, NO barriers ---------------
        // XCD-grouped swizzle (bijective on [0,400)): the 4 z-blocks sharing
        // the same 64 wf rows get consecutive swz -> same XCD L2 -> wf rows
        // fetched once per XCD instead of on 4 different XCDs.
        const int swz = (b & 7) * 50 + (b >> 3);
        const int by = swz >> 2, z = swz & 3;
        const int row0 = by * 64;
        const float* rowp = wf + (long long)(row0 + wv*16 + m16) * WF_LEN;
        const int kb = z * 256 + quad * 8;

        f32x4 acc[7];
        #pragma unroll
        for (int j = 0; j < 7; j++) acc[j] = f32x4{0.f, 0.f, 0.f, 0.f};

        #pragma unroll 2
        for (int cl = 0; cl < 8; ++cl) {
            short8 a_h, a_l;
            loadA_frag(rowp, kb + cl*32, WF_LEN, a_h, a_l);

            const short* fb = wwfF + (z*8 + cl) * WWF_STEP + lane * 8;
            short8 bh[7], bl[7];
            #pragma unroll
            for (int j = 0; j < 7; j++) {
                bh[j] = *(const short8*)(fb + j * 1024);
                bl[j] = *(const short8*)(fb + j * 1024 + 512);
            }
            #pragma unroll
            for (int j = 0; j < 7; j++) {
                acc[j] = __builtin_amdgcn_mfma_f32_16x16x32_bf16(a_h, bh[j], acc[j], 0, 0, 0);
                acc[j] = __builtin_amdgcn_mfma_f32_16x16x32_bf16(a_h, bl[j], acc[j], 0, 0, 0);
                acc[j] = __builtin_amdgcn_mfma_f32_16x16x32_bf16(a_l, bh[j], acc[j], 0, 0, 0);
            }
        }

        // f32 partial store (float4, disjoint per z -> deterministic)
        float* Cb = partT + (long long)z * PART_PER_Z;
        const int r = row0 + wv*16 + quad*4;          // 4-aligned, never crosses bb
        const int bb2 = r / N_WF, n = r - bb2 * N_WF;
        #pragma unroll
        for (int j = 0; j < 7; j++) {
            int cc = j * 16 + m16;
            if (cc >= WF_D) continue;
            float4 t;
            t.x = acc[j][0]; t.y = acc[j][1]; t.z = acc[j][2]; t.w = acc[j][3];
            *(float4*)&Cb[((long long)bb2 * PART_C + cc) * PART_N + n] = t;
        }
    } else {
        // ---------------- s2: direct-A, barriers only in epilogue ---------
        const int id2 = b - 400;
        const int bx = id2 & 3, by = id2 >> 2;
        const int row0 = by * 64, col0 = bx * 64;
        const float* rowp = ts + (long long)(row0 + wv*16 + m16) * TS_F;

        f32x4 acc[4];
        #pragma unroll
        for (int j = 0; j < 4; j++) acc[j] = f32x4{0.f, 0.f, 0.f, 0.f};

        #pragma unroll
        for (int st = 0; st < S2_NSTEP; ++st) {
            short8 a_h, a_l;
            loadA_frag(rowp, st*32 + quad*8, TS_F, a_h, a_l);

            const short* fb = wtsF + st * WTS_STEP + (bx*4) * 1024 + lane * 8;
            #pragma unroll
            for (int j = 0; j < 4; j++) {
                short8 b_h = *(const short8*)(fb + j * 1024);
                short8 b_l = *(const short8*)(fb + j * 1024 + 512);
                acc[j] = __builtin_amdgcn_mfma_f32_16x16x32_bf16(a_h, b_h, acc[j], 0, 0, 0);
                acc[j] = __builtin_amdgcn_mfma_f32_16x16x32_bf16(a_h, b_l, acc[j], 0, 0, 0);
                acc[j] = __builtin_amdgcn_mfma_f32_16x16x32_bf16(a_l, b_h, acc[j], 0, 0, 0);
            }
        }

        // epilogue: tanh -> LDS [64][66] transpose -> short8 featA stores
        #pragma unroll
        for (int j = 0; j < 4; j++) {
            float bv = b_ts[col0 + j*16 + m16];
            #pragma unroll
            for (int rr = 0; rr < 4; rr++)
                smemF[(wv*16 + quad*4 + rr)*66 + j*16 + m16] = tanhf(acc[j][rr] + bv);
        }
        __syncthreads();
        #pragma unroll
        for (int i = 0; i < 2; i++) {
            int task = i*256 + tid;          // 512 tasks = 64 rows x 8 col-groups
            int rl = task >> 3, cg = task & 7;
            const float* p = &smemF[rl*66 + cg*8];
            short8 h8, l8;
            #pragma unroll
            for (int q = 0; q < 8; q++) { short h, s; split_bf16(p[q], h, s); h8[q]=h; l8[q]=s; }
            long long fo = fa_addr(row0 + rl, col0 + cg*8);
            *(short8*)(featAH + fo) = h8;
            *(short8*)(featAL + fo) = l8;
        }
    }
}

// ---- K2: reduce z-slices -> wfo3F frag layout + w1F pack ------------------
__global__ __launch_bounds__(256)
void k2_reduce(const float* __restrict__ partT, const float* __restrict__ b_wf,
               const float* __restrict__ W1,
               short* __restrict__ wfo3F, short* __restrict__ w1F)
{
    const int blk = blockIdx.x, tid = threadIdx.x;
    if (blk < 448) {
        const int bb = blk / 14, rem = blk % 14;
        const int st = rem >> 1, half = rem & 1;
        const int j = half * 4 + (tid >> 6);
        const int g = tid & 63;
        const int m16 = g & 15, kk8 = g >> 4;
        const int c = j * 16 + m16;
        const int n = st * 32 + kk8 * 8;

        float v[8];
        if (c < WF_D && n < N_WF) {
            float bw = b_wf[c];
            #pragma unroll
            for (int q = 0; q < 8; q++) v[q] = bw;
            #pragma unroll
            for (int z = 0; z < S1_Z; z++) {
                const float* p = partT + (long long)z * PART_PER_Z
                               + ((long long)bb * PART_C + c) * PART_N + n;
                float4 t0 = ((const float4*)p)[0];
                float4 t1 = ((const float4*)p)[1];
                v[0]+=t0.x; v[1]+=t0.y; v[2]+=t0.z; v[3]+=t0.w;
                v[4]+=t1.x; v[5]+=t1.y; v[6]+=t1.z; v[7]+=t1.w;
            }
        } else {
            #pragma unroll
            for (int q = 0; q < 8; q++) v[q] = 0.f;
        }
        short8 h8, l8;
        #pragma unroll
        for (int q = 0; q < 8; q++) { short h, s; split_bf16(v[q], h, s); h8[q]=h; l8[q]=s; }
        long long base = (long long)bb * WFO3_PER_B + st * (K3_NJ*1024) + j * 1024 + g * 8;
        *(short8*)(wfo3F + base)       = h8;
        *(short8*)(wfo3F + base + 512) = l8;
    } else {                            // w1F pack: 19 chunks x 16 tiles x 64 lanes
        int idx = (blk-448)*256 + tid;  // [0,19456)
        int l = idx & 63, t = idx >> 6;
        int jj = t & 15, ch = t >> 4;
        int n = jj*16 + (l&15), lq = l >> 4;
        short8 h8, l8;
        #pragma unroll
        for (int q = 0; q < 8; q++) {
            int k = ch*32 + lq*8 + q;    // K-order index [0,608)
            float v = 0.f;
            if (k < 200)                  v = W1[k*FC_H + n];
            else if (k >= 224 && k < 580) v = W1[(k-24)*FC_H + n];
            short h, s; split_bf16(v, h, s); h8[q]=h; l8[q]=s;
        }
        int off = (ch*16 + jj)*1024 + l*8;
        *(short8*)(w1F + off)       = h8;
        *(short8*)(w1F + off + 512) = l8;
    }
}

// ====== K4 fused (R16-proven): XCD-grouped swizzle; phase A = s3 spread
//   into LDS A-frags; phase B = s4 pipeline (chunks 0..14 global staged,
//   15..18 from LDS); LDS cross-wave reduce head epilogue. =================
__global__ __launch_bounds__(512)
void k4_fused(const float* __restrict__ wwm, const float* __restrict__ texts,
              const short* __restrict__ wfo3F,
              const short* __restrict__ featAH, const short* __restrict__ featAL,
              const short* __restrict__ w1F,
              const float* __restrict__ b1, const float* __restrict__ W2,
              const float* __restrict__ b2, float* __restrict__ out)
{
    __shared__ short AhB[2][2048], AlB[2][2048];   // 16 KB A dbuf (phase B)
    __shared__ short fLH[4][2048], fLL[4][2048];   // 32 KB spread A-frags
    __shared__ float transF[64*132];               // 33.8 KB (phase A only)
    __shared__ float ored[8][64][2];               // 4 KB (epilogue)

    const int tid = threadIdx.x;
    const int wv = tid >> 6, lane = tid & 63;
    const int m16 = lane & 15, quad = lane >> 4;
    // XCD-grouped swizzle (bijective on [0,256))
    const int bid = blockIdx.x;
    const int rt = ((bid & 7) << 5) | (bid >> 3);
    const int row0 = rt * 64;
    const int fsw = (quad ^ ((m16 >> 1) & 3)) * 8;

    // ---------------- Phase A: s3 for this block's 64 rows ----------------
    {
        const int bz = rt >> 3, by = rt & 7;
        const int bx3 = wv >> 2, wrow = wv & 3;
        const float* rowp3 = wwm + ((long long)bz * TT + by*64 + wrow*16 + m16) * N_WF;
        const short* FB = wfo3F + (long long)bz * WFO3_PER_B;

        f32x4 acc3[4];
        #pragma unroll
        for (int j = 0; j < 4; j++) acc3[j] = f32x4{0.f, 0.f, 0.f, 0.f};

        #pragma unroll 2
        for (int st = 0; st < K3_NSTEP; ++st) {
            short8 a_h, a_l;
            loadA_frag(rowp3, st*32 + quad*8, N_WF, a_h, a_l);
            const short* fb = FB + st * (K3_NJ*1024) + (bx3*4) * 1024 + lane * 8;
            #pragma unroll
            for (int j = 0; j < 4; j++) {
                short8 b_h = *(const short8*)(fb + j * 1024);
                short8 b_l = *(const short8*)(fb + j * 1024 + 512);
                acc3[j] = __builtin_amdgcn_mfma_f32_16x16x32_bf16(a_h, b_h, acc3[j], 0, 0, 0);
                acc3[j] = __builtin_amdgcn_mfma_f32_16x16x32_bf16(a_h, b_l, acc3[j], 0, 0, 0);
                acc3[j] = __builtin_amdgcn_mfma_f32_16x16x32_bf16(a_l, b_h, acc3[j], 0, 0, 0);
            }
        }
        // transpose stage: rows 0..63 x cols 0..127 (cols>=100 zero via wfo3F pad)
        #pragma unroll
        for (int j = 0; j < 4; j++)
            #pragma unroll
            for (int rr = 0; rr < 4; rr++)
                transF[(wrow*16 + quad*4 + rr)*132 + bx3*64 + j*16 + m16] =
                    acc3[j][rr] * (1.0f / N_WF);
    }
    __syncthreads();
    // build spread A-frags in LDS: 1024 slots = [cf 4][ri 4][lane 64]
    #pragma unroll
    for (int i = 0; i < 2; i++) {
        int slot = tid*2 + i;
        int l = slot & 63, ri = (slot >> 6) & 3, cf = slot >> 8;
        int lrow = l & 15, cg = l >> 4;
        const float* p = &transF[(ri*16 + lrow)*132 + cf*32 + cg*8];
        short8 h8, l8;
        #pragma unroll
        for (int q = 0; q < 8; q++) { short h, s; split_bf16(p[q], h, s); h8[q]=h; l8[q]=s; }
        *(short8*)&fLH[cf][(ri << 9) + l*8] = h8;
        *(short8*)&fLL[cf][(ri << 9) + l*8] = l8;
    }
    __syncthreads();

    // ---------------- Phase B: s4 pipeline --------------------------------
    const int ar  = tid >> 2;
    const int ag  = tid & 3;
    const int asw = (ag ^ ((ar >> 1) & 3)) * 8;
    const long long gr = row0 + ar;
    const int t8 = (tid & 255) * 8;

    f32x4 acc[4][2];
    #pragma unroll
    for (int i = 0; i < 4; i++)
        #pragma unroll
        for (int j = 0; j < 2; j++) acc[i][j] = f32x4{0.f, 0.f, 0.f, 0.f};

    float  vaP[8], vaQ[8];
    short8 vfaP, vfaQ;
    short8 vbhP[2], vblP[2], vbhQ[2], vblQ[2];

    auto loadTexts = [&](int c, float* va) {
        if (tid < 256) {
            int kc = c * 32 + ag * 8;
            if (kc + 8 <= TEXT_D) {
                const float4* p = (const float4*)(texts + gr * TEXT_D + kc);
                float4 t0 = p[0], t1 = p[1];
                va[0]=t0.x; va[1]=t0.y; va[2]=t0.z; va[3]=t0.w;
                va[4]=t1.x; va[5]=t1.y; va[6]=t1.z; va[7]=t1.w;
            } else {
                #pragma unroll
                for (int q = 0; q < 8; q++) va[q] = 0.f;
            }
        }
    };
    auto loadFeat = [&](int c, short8& vfa) {
        long long base = (((long long)rt * 8 + (c - 7)) << 11) + t8;
        vfa = *(const short8*)(((tid < 256) ? featAH : featAL) + base);
    };
    auto loadAP = [&](int c) { if (c < 7) loadTexts(c, vaP); else loadFeat(c, vfaP); };
    auto loadAQ = [&](int c) { if (c < 7) loadTexts(c, vaQ); else loadFeat(c, vfaQ); };

    auto storeTexts = [&](const float* va, int buf) {
        if (tid < 256) {
            short8 h8, l8;
            #pragma unroll
            for (int q = 0; q < 8; q++) { short h, s; split_bf16(va[q], h, s); h8[q]=h; l8[q]=s; }
            *(short8*)&AhB[buf][ar*32 + asw] = h8;
            *(short8*)&AlB[buf][ar*32 + asw] = l8;
        }
    };
    auto storeFeat = [&](const short8& vfa, int buf) {
        short* dst = (tid < 256) ? AhB[buf] : AlB[buf];
        *(short8*)&dst[t8] = vfa;
    };
    auto storeAP = [&](int c, int buf) { if (c < 7) storeTexts(vaP, buf); else storeFeat(vfaP, buf); };
    auto storeAQ = [&](int c, int buf) { if (c < 7) storeTexts(vaQ, buf); else storeFeat(vfaQ, buf); };

    auto loadBP = [&](int c) {
        #pragma unroll
        for (int ci = 0; ci < 2; ci++) {
            const short* fb = w1F + (c * 16 + wv * 2 + ci) * 1024 + lane * 8;
            vbhP[ci] = *(const short8*)fb;
            vblP[ci] = *(const short8*)(fb + 512);
        }
    };
    auto loadBQ = [&](int c) {
        #pragma unroll
        for (int ci = 0; ci < 2; ci++) {
            const short* fb = w1F + (c * 16 + wv * 2 + ci) * 1024 + lane * 8;
            vbhQ[ci] = *(const short8*)fb;
            vblQ[ci] = *(const short8*)(fb + 512);
        }
    };

    auto mfmaChunk = [&](int c, int buf, const short8 bh[2], const short8 bl[2]) {
        short8 a_h[4], a_l[4];
        if (c < 7) {
            #pragma unroll
            for (int ri = 0; ri < 4; ri++) {
                a_h[ri] = *(const short8*)&AhB[buf][(ri*16 + m16)*32 + fsw];
                a_l[ri] = *(const short8*)&AlB[buf][(ri*16 + m16)*32 + fsw];
            }
        } else {
            #pragma unroll
            for (int ri = 0; ri < 4; ri++) {
                a_h[ri] = *(const short8*)&AhB[buf][ri*512 + lane*8];
                a_l[ri] = *(const short8*)&AlB[buf][ri*512 + lane*8];
            }
        }
        #pragma unroll
        for (int ci = 0; ci < 2; ci++)
            #pragma unroll
            for (int ri = 0; ri < 4; ri++) {
                acc[ri][ci] = __builtin_amdgcn_mfma_f32_16x16x32_bf16(a_h[ri], bh[ci], acc[ri][ci], 0, 0, 0);
                acc[ri][ci] = __builtin_amdgcn_mfma_f32_16x16x32_bf16(a_h[ri], bl[ci], acc[ri][ci], 0, 0, 0);
                acc[ri][ci] = __builtin_amdgcn_mfma_f32_16x16x32_bf16(a_l[ri], bh[ci], acc[ri][ci], 0, 0, 0);
            }
    };

    // prologue: chunks 0 (P) and 1 (Q) in flight; chunk 0 staged
    loadAP(0); loadBP(0);
    loadAQ(1); loadBQ(1);
    storeAP(0, 0);
    __syncthreads();

    for (int c = 0; c < K4G_NCH; c += 2) {
        // even chunk c (buf 0)
        {
            short8 bh[2] = {vbhP[0], vbhP[1]};
            short8 bl[2] = {vblP[0], vblP[1]};
            if (c + 2 < K4G_NCH) { loadAP(c + 2); loadBP(c + 2); }
            mfmaChunk(c, 0, bh, bl);
            if (c + 1 < K4G_NCH) { storeAQ(c + 1, 1); __syncthreads(); }
        }
        // odd chunk c+1 (buf 1)
        if (c + 1 < K4G_NCH) {
            short8 bh[2] = {vbhQ[0], vbhQ[1]};
            short8 bl[2] = {vblQ[0], vblQ[1]};
            if (c + 3 < K4G_NCH) { loadAQ(c + 3); loadBQ(c + 3); }
            mfmaChunk(c + 1, 1, bh, bl);
            if (c + 2 < K4G_NCH) { storeAP(c + 2, 0); __syncthreads(); }
        }
    }

    // chunks 15..18: A from LDS spread frags, B from L2 (8-wave TLP hides it)
    #pragma unroll
    for (int c = 15; c < 19; ++c) {
        short8 bh[2], bl[2];
        #pragma unroll
        for (int ci = 0; ci < 2; ci++) {
            const short* fb = w1F + (c * 16 + wv * 2 + ci) * 1024 + lane * 8;
            bh[ci] = *(const short8*)fb;
            bl[ci] = *(const short8*)(fb + 512);
        }
        const int f = c - 15;
        short8 a_h[4], a_l[4];
        #pragma unroll
        for (int ri = 0; ri < 4; ri++) {
            a_h[ri] = *(const short8*)&fLH[f][ri*512 + lane*8];
            a_l[ri] = *(const short8*)&fLL[f][ri*512 + lane*8];
        }
        #pragma unroll
        for (int ci = 0; ci < 2; ci++)
            #pragma unroll
            for (int ri = 0; ri < 4; ri++) {
                acc[ri][ci] = __builtin_amdgcn_mfma_f32_16x16x32_bf16(a_h[ri], bh[ci], acc[ri][ci], 0, 0, 0);
                acc[ri][ci] = __builtin_amdgcn_mfma_f32_16x16x32_bf16(a_h[ri], bl[ci], acc[ri][ci], 0, 0, 0);
                acc[ri][ci] = __builtin_amdgcn_mfma_f32_16x16x32_bf16(a_l[ri], bh[ci], acc[ri][ci], 0, 0, 0);
            }
    }

    // epilogue: relu + head partials, per-wave 16-lane reduce, LDS cross-wave
    float o0[4][4] = {}, o1[4][4] = {};
    #pragma unroll
    for (int ci = 0; ci < 2; ci++) {
        int C = wv * 32 + ci * 16 + m16;
        float bv  = b1[C];
        float w20 = W2[C * 2 + 0];
        float w21 = W2[C * 2 + 1];
        #pragma unroll
        for (int ri = 0; ri < 4; ri++)
            #pragma unroll
            for (int rr = 0; rr < 4; rr++) {
                float v = fmaxf(acc[ri][ci][rr] + bv, 0.f);
                o0[ri][rr] += v * w20;
                o1[ri][rr] += v * w21;
            }
    }
    __syncthreads();
    #pragma unroll
    for (int ri = 0; ri < 4; ri++)
        #pragma unroll
        for (int rr = 0; rr < 4; rr++) {
            float s0 = o0[ri][rr], s1 = o1[ri][rr];
            #pragma unroll
            for (int mk = 1; mk < 16; mk <<= 1) {
                s0 += __shfl_xor(s0, mk);
                s1 += __shfl_xor(s1, mk);
            }
            if (m16 == 0) {
                int rl = ri * 16 + quad * 4 + rr;
                ored[wv][rl][0] = s0;
                ored[wv][rl][1] = s1;
            }
        }
    __syncthreads();
    if (tid < 128) {
        int rl = tid >> 1, cc = tid & 1;
        float s = b2[cc];
        #pragma unroll
        for (int w = 0; w < 8; w++) s += ored[w][rl][cc];
        out[(long long)(row0 + rl) * 2 + cc] = s;
    }
}

extern "C" void kernel_launch(void* const* d_in, const int* in_sizes, int n_in,
                              void* d_out, int out_size, void* d_ws, size_t ws_size,
                              hipStream_t stream)
{
    const float* texts = (const float*)d_in[0];   // (512,32,200)
    const float* ts    = (const float*)d_in[1];   // (512,32,76)
    const float* wf    = (const float*)d_in[2];   // (32,200,1000)
    const float* wwm   = (const float*)d_in[3];   // (32,512,200)
    const float* W_wf  = (const float*)d_in[4];   // (1000,100)
    const float* b_wf  = (const float*)d_in[5];
    const float* W_ts  = (const float*)d_in[6];   // (76,256)
    const float* b_ts  = (const float*)d_in[7];
    const float* W1    = (const float*)d_in[8];   // (556,256)
    const float* b1    = (const float*)d_in[9];
    const float* W2    = (const float*)d_in[10];  // (256,2)
    const float* b2    = (const float*)d_in[11];
    float* out = (float*)d_out;

    // ---- workspace layout (all disjoint, ~35 MB) ----
    float* partT  = (float*)d_ws;                      // 4*802816 f32
    short* wwfF   = (short*)(partT + S1_Z * PART_PER_Z);
    short* wtsF   = wwfF + WWF_TOT;
    short* w1F    = wtsF + WTS_TOT;
    short* wfo3F  = w1F + W1F_TOT;
    short* featAH = wfo3F + WFO3_TOT;                  // ts_out frag planes
    short* featAL = featAH + FA_TOT;

    // 0) packs k1 needs (wwfF, wtsF)
    k0_prep<<<68, 256, 0, stream>>>(W_wf, W_ts, wwfF, wtsF);

    // 1) s1 split-K partials (XCD-grouped z) + s2 (featA cf 0..7)
    k1_main<<<1424, 256, 0, stream>>>(wf, ts, b_ts, wwfF, wtsF,
                                      partT, featAH, featAL);

    // 2) reduce -> wfo3F frag layout + w1F pack
    k2_reduce<<<524, 256, 0, stream>>>(partT, b_wf, W1, wfo3F, w1F);

    // 3) fused s3 + s4 + head (XCD-grouped swizzle)
    k4_fused<<<ROWS / 64, 512, 0, stream>>>(wwm, texts, wfo3F,
                                            featAH, featAL,
                                            w1F, b1, W2, b2, out);
}